// Round 2
// baseline (47.968 us; speedup 1.0000x reference)
//
#include <hip/hip_runtime.h>
#include <hip/hip_bf16.h>
#include <math.h>

// Problem constants (from reference setup_inputs)
#define B_ROWS 256
#define D_IN   128
#define D_OUT  256
#define M_LEN  4096
#define BETA   50.0f

// out layout (f32): loss[256] | mem_out[4096*256] | md_out[4096*128]
#define OFF_MEM  (B_ROWS)
#define OFF_MD   (B_ROWS + M_LEN * D_OUT)

// ---------------------------------------------------------------------------
// K1 (k_prep): enc = tanh(norm(x)@W1+b1), copy memory->out, mem_data->out,
// init loss to +inf bits. 256 blocks x 256 threads.
// ---------------------------------------------------------------------------
__global__ __launch_bounds__(256) void k_prep(
    const float* __restrict__ x, const float* __restrict__ mean,
    const float* __restrict__ stdv, const float* __restrict__ W1,
    const float* __restrict__ b1,
    const float4* __restrict__ mem4, const float4* __restrict__ md4,
    float* __restrict__ enc, float* __restrict__ out) {
  __shared__ float sx[D_IN];
  const int b = blockIdx.x, j = threadIdx.x;
  const int tid = b * 256 + j;

  // issue copy loads early (latency overlaps the dot product below)
  float4 c0 = mem4[tid];
  float4 c1 = mem4[65536 + tid];
  float4 c2 = mem4[2 * 65536 + tid];
  float4 c3 = mem4[3 * 65536 + tid];
  float4 e0 = md4[tid];
  float4 e1 = md4[65536 + tid];

  if (j < D_IN) {
    float s = stdv[j];
    sx[j] = (s == 0.0f) ? 0.0f : (x[b * D_IN + j] - mean[j]) / s;
  }
  __syncthreads();

  float acc = b1[j];
#pragma unroll 8
  for (int k = 0; k < D_IN; ++k) acc = fmaf(sx[k], W1[k * D_OUT + j], acc);
  enc[b * D_OUT + j] = tanhf(acc);

  float4* mo = (float4*)(out + OFF_MEM);  // 1KB offset, 16B aligned
  float4* dd = (float4*)(out + OFF_MD);
  mo[tid] = c0; mo[65536 + tid] = c1; mo[2 * 65536 + tid] = c2; mo[3 * 65536 + tid] = c3;
  dd[tid] = e0; dd[65536 + tid] = e1;
  if (b == 0) ((unsigned int*)out)[j] = 0x7F800000u;  // +inf (loss init)
}

// ---------------------------------------------------------------------------
// K2 (k_dist): loss[b] = min_m sum_d |enc[b,d] - memory[m,d]|
// 512 blocks (64 m-tiles x 8 b-tiles) x 128 threads; tile 32b x 64m,
// 4x4 micro-tile; k-chunks of 64, double-buffered LDS, 1 barrier/chunk.
// LDS tiles are [k][row] transposed with f4-granular XOR swizzle so both
// the b32 staging scatter-writes and b128 fragment reads are <=2-way.
// ---------------------------------------------------------------------------
#define TKC 64

__global__ __launch_bounds__(128) void k_dist(const float* __restrict__ enc,
                                              const float* __restrict__ mem,
                                              float* __restrict__ out) {
  __shared__ __align__(16) float sE[2 * TKC * 32];  // [buf][k][32] swizzled
  __shared__ __align__(16) float sM[2 * TKC * 64];  // [buf][k][64] swizzled
  __shared__ float red[32 * 17];

  const int t  = threadIdx.x;   // 0..127
  const int tr = t >> 4;        // 0..7   (4 b-rows each)
  const int tc = t & 15;        // 0..15  (4 m-rows each; also staging k-f4 idx)
  const int m0 = blockIdx.x * 64;
  const int b0 = blockIdx.y * 32;

  float acc[4][4] = {};
  float4 rE[4], rM[8];

  auto load_chunk = [&](int kc) {
    const float* ep = enc + (b0 + tr) * D_OUT + kc * TKC + tc * 4;
#pragma unroll
    for (int i = 0; i < 4; ++i) rE[i] = *(const float4*)(ep + i * 8 * D_OUT);
    const float* mp = mem + (m0 + tr) * D_OUT + kc * TKC + tc * 4;
#pragma unroll
    for (int i = 0; i < 8; ++i) rM[i] = *(const float4*)(mp + i * 8 * D_OUT);
  };

  auto store_chunk = [&](int bsel) {
    float* dE = sE + bsel * (TKC * 32);
    float* dM = sM + bsel * (TKC * 64);
    const int swzE = (tc & 7) << 2;  // ((k>>2)&7)<<2, k = 4*tc+c
    const int swzM = tc << 2;        // ((k>>2)&15)<<2
#pragma unroll
    for (int i = 0; i < 4; ++i) {
      int base = tc * 128 + ((tr + 8 * i) ^ swzE);  // (4tc+c)*32 + row^swz
      dE[base]      = rE[i].x;
      dE[base + 32] = rE[i].y;
      dE[base + 64] = rE[i].z;
      dE[base + 96] = rE[i].w;
    }
#pragma unroll
    for (int i = 0; i < 8; ++i) {
      int base = tc * 256 + ((tr + 8 * i) ^ swzM);  // (4tc+c)*64 + row^swz
      dM[base]       = rM[i].x;
      dM[base + 64]  = rM[i].y;
      dM[base + 128] = rM[i].z;
      dM[base + 192] = rM[i].w;
    }
  };

  auto compute_chunk = [&](int bsel) {
    const float* pE = sE + bsel * (TKC * 32);
    const float* pM = sM + bsel * (TKC * 64);
#pragma unroll 4
    for (int q = 0; q < 16; ++q) {  // q = k>>2 within chunk
      const float* qE = pE + q * 128 + ((tr ^ (q & 7)) << 2);
      const float* qM = pM + q * 256 + ((tc ^ q) << 2);
#pragma unroll
      for (int c = 0; c < 4; ++c) {
        float4 a  = *(const float4*)(qE + c * 32);
        float4 bv = *(const float4*)(qM + c * 64);
        float av[4] = {a.x, a.y, a.z, a.w};
        float bw[4] = {bv.x, bv.y, bv.z, bv.w};
#pragma unroll
        for (int i = 0; i < 4; ++i)
#pragma unroll
          for (int j2 = 0; j2 < 4; ++j2)
            acc[i][j2] += fabsf(av[i] - bw[j2]);
      }
    }
  };

  load_chunk(0);
  store_chunk(0);
  __syncthreads();

  for (int kc = 0; kc < 4; ++kc) {
    const int cur = kc & 1;
    if (kc < 3) load_chunk(kc + 1);   // prefetch into regs (vmcnt waits after compute)
    compute_chunk(cur);
    if (kc < 3) store_chunk(cur ^ 1); // write next buffer
    __syncthreads();
  }

  // per-thread min over its 4 m-cols, per b-row
#pragma unroll
  for (int i = 0; i < 4; ++i) {
    float m1 = fminf(fminf(acc[i][0], acc[i][1]), fminf(acc[i][2], acc[i][3]));
    red[(tr * 4 + i) * 17 + tc] = m1;
  }
  __syncthreads();

  if (t < 32) {
    float m = red[t * 17];
#pragma unroll
    for (int c = 1; c < 16; ++c) m = fminf(m, red[t * 17 + c]);
    // distances >= 0, init is +inf -> uint bit-pattern atomicMin valid
    atomicMin((unsigned int*)out + (b0 + t), __float_as_uint(m));
  }
}

// ---------------------------------------------------------------------------
// K3 (k_scatter): sequential circular-buffer update collapsed to
// ballot/prefix + scatter (count starts at M_LEN so positions wrap from 0).
// ---------------------------------------------------------------------------
__global__ __launch_bounds__(256) void k_scatter(float* __restrict__ out,
                                                 const float* __restrict__ enc,
                                                 const float* __restrict__ x) {
  __shared__ int wcount[4];
  int t = threadIdx.x;
  float l = out[t];  // final loss
  bool cond = isfinite(l) && (l <= BETA);
  unsigned long long m = __ballot(cond);
  int lane = t & 63;
  int wv   = t >> 6;
  int pre_in_wave = __popcll(m & ((1ull << lane) - 1ull));
  if (lane == 0) wcount[wv] = (int)__popcll(m);
  __syncthreads();
  int base = 0;
  for (int w = 0; w < wv; ++w) base += wcount[w];
  if (cond) {
    int pos = base + pre_in_wave;  // (M_LEN + prefix) % M_LEN
    float* mrow = out + OFF_MEM + pos * D_OUT;
    const float* erow = enc + t * D_OUT;
    for (int d = 0; d < D_OUT; ++d) mrow[d] = erow[d];
    float* drow = out + OFF_MD + pos * D_IN;
    const float* xrow = x + t * D_IN;
    for (int d = 0; d < D_IN; ++d) drow[d] = xrow[d];
  }
}

// ---------------------------------------------------------------------------
extern "C" void kernel_launch(void* const* d_in, const int* in_sizes, int n_in,
                              void* d_out, int out_size, void* d_ws, size_t ws_size,
                              hipStream_t stream) {
  const float* x      = (const float*)d_in[0];
  const float* mean   = (const float*)d_in[1];
  const float* stdv   = (const float*)d_in[2];
  const float* W1     = (const float*)d_in[3];
  const float* b1     = (const float*)d_in[4];
  const float* memory = (const float*)d_in[5];
  const float* memdat = (const float*)d_in[6];
  float* out = (float*)d_out;
  float* enc = (float*)d_ws;  // 256*256*4 = 256KB scratch

  k_prep<<<dim3(B_ROWS), dim3(256), 0, stream>>>(
      x, mean, stdv, W1, b1, (const float4*)memory, (const float4*)memdat, enc, out);

  k_dist<<<dim3(M_LEN / 64, B_ROWS / 32), dim3(128), 0, stream>>>(enc, memory, out);

  k_scatter<<<dim3(1), dim3(256), 0, stream>>>(out, enc, x);
}

// Round 4
// 45.392 us; speedup vs baseline: 1.0568x; 1.0568x over previous
//
#include <hip/hip_runtime.h>
#include <hip/hip_bf16.h>
#include <math.h>

// Problem constants (from reference setup_inputs)
#define B_ROWS 256
#define D_IN   128
#define D_OUT  256
#define M_LEN  4096
#define BETA   50.0f

// out layout (f32): loss[256] | mem_out[4096*256] | md_out[4096*128]
#define OFF_MEM  (B_ROWS)
#define OFF_MD   (B_ROWS + M_LEN * D_OUT)

// ---------------------------------------------------------------------------
// K1 (k_prep): enc = tanh(norm(x)@W1+b1) and loss init to +inf.
// 256 blocks x 256 threads (one block per batch row).
// ---------------------------------------------------------------------------
__global__ __launch_bounds__(256) void k_prep(
    const float* __restrict__ x, const float* __restrict__ mean,
    const float* __restrict__ stdv, const float* __restrict__ W1,
    const float* __restrict__ b1, float* __restrict__ enc,
    float* __restrict__ out) {
  __shared__ float sx[D_IN];
  const int b = blockIdx.x, j = threadIdx.x;
  if (j < D_IN) {
    float s = stdv[j];
    sx[j] = (s == 0.0f) ? 0.0f : (x[b * D_IN + j] - mean[j]) / s;
  }
  __syncthreads();
  float acc = b1[j];
#pragma unroll 8
  for (int k = 0; k < D_IN; ++k) acc = fmaf(sx[k], W1[k * D_OUT + j], acc);
  enc[b * D_OUT + j] = tanhf(acc);
  if (b == 0) ((unsigned int*)out)[j] = 0x7F800000u;  // +inf loss init
}

// ---------------------------------------------------------------------------
// K2 (k_dist): loss[b] = min_m sum_d |enc[b,d] - memory[m,d]|
// 512 blocks (64 m-tiles x 8 b-tiles) x 256 threads.
// 2-way k-split: waves 0-1 do k[0,128), waves 2-3 do k[128,256); partials
// summed via LDS at the end. Per half: 8x16 threads x 4x4 microtile on a
// 32b x 64m tile; TK=32 chunks, double-buffered LDS, 1 barrier per chunk.
// LDS layout [k][row] transposed; E-tile rows XOR-swizzled by 4*(k>>2) so
// staging b32 scatter-writes and b128 fragment reads are <=2-way (free).
// Also performs the FULL memory->out / mem_data->out copy: each thread
// carries 2 mem float4 + 1 md float4 (512+256 float4 per block = exact).
// ---------------------------------------------------------------------------
#define TB 32
#define TM 64
#define TK 32

__global__ __launch_bounds__(256) void k_dist(
    const float* __restrict__ enc, const float* __restrict__ mem,
    const float4* __restrict__ mem4, const float4* __restrict__ md4,
    float* __restrict__ out) {
  __shared__ __align__(16) float sE[2][2][TK][TB];  // [half][buf][k][brow] 16KB
  __shared__ __align__(16) float sM[2][2][TK][TM];  // [half][buf][k][mrow] 32KB

  const int t   = threadIdx.x;
  const int h   = t >> 7;        // k-half (0: waves 0-1, 1: waves 2-3)
  const int th  = t & 127;
  const int tr  = th >> 4;       // 0..7  -> b-rows tr*4..tr*4+3
  const int tc  = th & 15;       // 0..15 -> m-rows tc*4..tc*4+3
  const int m0  = blockIdx.x * TM;
  const int b0  = blockIdx.y * TB;
  const int bid = blockIdx.y * 64 + blockIdx.x;  // gridDim.x == 64
  const int koff = h * (D_OUT / 2);

  // fused output copy: issue loads now, complete stores at the end.
  // per block: 512 float4 of memory + 256 float4 of mem_data (exact coverage)
  float4 cm0 = mem4[bid * 512 + t];
  float4 cm1 = mem4[bid * 512 + 256 + t];
  float4 cd0 = md4[bid * 256 + t];

  float4 rE[2], rM[4];
  float acc[4][4] = {};

  auto load_g = [&](int kc) {
    const int kb = koff + kc * TK;
#pragma unroll
    for (int i = 0; i < 2; ++i) {
      int f = 2 * th + i, row = f >> 3, kg = f & 7;
      rE[i] = *(const float4*)(enc + (b0 + row) * D_OUT + kb + kg * 4);
    }
#pragma unroll
    for (int i = 0; i < 4; ++i) {
      int f = 4 * th + i, row = f >> 3, kg = f & 7;
      rM[i] = *(const float4*)(mem + (m0 + row) * D_OUT + kb + kg * 4);
    }
  };

  auto store_s = [&](int bf) {
#pragma unroll
    for (int i = 0; i < 2; ++i) {
      int f = 2 * th + i, row = f >> 3, kg = f & 7;
      int rsw = row ^ (kg * 4);  // swizzle: spreads banks for write & read
      sE[h][bf][kg * 4 + 0][rsw] = rE[i].x;
      sE[h][bf][kg * 4 + 1][rsw] = rE[i].y;
      sE[h][bf][kg * 4 + 2][rsw] = rE[i].z;
      sE[h][bf][kg * 4 + 3][rsw] = rE[i].w;
    }
#pragma unroll
    for (int i = 0; i < 4; ++i) {
      int f = 4 * th + i, row = f >> 3, kg = f & 7;
      sM[h][bf][kg * 4 + 0][row] = rM[i].x;
      sM[h][bf][kg * 4 + 1][row] = rM[i].y;
      sM[h][bf][kg * 4 + 2][row] = rM[i].z;
      sM[h][bf][kg * 4 + 3][row] = rM[i].w;
    }
  };

  auto compute = [&](int bf) {
#pragma unroll
    for (int k = 0; k < TK; ++k) {
      const int kg = k >> 2;
      float4 a  = *(const float4*)&sE[h][bf][k][(tr * 4) ^ (kg * 4)];
      float4 bv = *(const float4*)&sM[h][bf][k][tc * 4];
      float av[4] = {a.x, a.y, a.z, a.w};
      float bw[4] = {bv.x, bv.y, bv.z, bv.w};
#pragma unroll
      for (int i = 0; i < 4; ++i)
#pragma unroll
        for (int j = 0; j < 4; ++j)
          acc[i][j] += fabsf(av[i] - bw[j]);
    }
  };

  load_g(0);
  store_s(0);
  __syncthreads();

  for (int kc = 0; kc < 4; ++kc) {
    if (kc < 3) load_g(kc + 1);       // global prefetch (latency under compute)
    compute(kc & 1);
    if (kc < 3) store_s((kc + 1) & 1);
    __syncthreads();
  }

  // combine k-halves: half 1 dumps partials, half 0 sums + min-reduces
  float* scratch = &sE[0][0][0][0];   // 4096 floats available, need 2048
  if (h == 1) {
#pragma unroll
    for (int i = 0; i < 4; ++i)
#pragma unroll
      for (int j = 0; j < 4; ++j)
        scratch[(i * 4 + j) * 128 + th] = acc[i][j];
  }
  __syncthreads();
  if (h == 0) {
#pragma unroll
    for (int i = 0; i < 4; ++i) {
#pragma unroll
      for (int j = 0; j < 4; ++j) acc[i][j] += scratch[(i * 4 + j) * 128 + th];
      float m1 = fminf(fminf(acc[i][0], acc[i][1]),
                       fminf(acc[i][2], acc[i][3]));
      m1 = fminf(m1, __shfl_xor(m1, 1));
      m1 = fminf(m1, __shfl_xor(m1, 2));
      m1 = fminf(m1, __shfl_xor(m1, 4));
      m1 = fminf(m1, __shfl_xor(m1, 8));
      if (tc == 0)  // distances >= 0, init +inf -> uint-bit atomicMin valid
        atomicMin((unsigned int*)out + (b0 + tr * 4 + i), __float_as_uint(m1));
    }
  }

  // complete fused copy
  float4* mo = (float4*)(out + OFF_MEM);
  float4* dd = (float4*)(out + OFF_MD);
  mo[bid * 512 + t] = cm0;
  mo[bid * 512 + 256 + t] = cm1;
  dd[bid * 256 + t] = cd0;
}

// ---------------------------------------------------------------------------
// K3 (k_scatter): sequential circular-buffer update collapsed to
// ballot/prefix + scatter (count starts at M_LEN so positions wrap from 0).
// ---------------------------------------------------------------------------
__global__ __launch_bounds__(256) void k_scatter(float* __restrict__ out,
                                                 const float* __restrict__ enc,
                                                 const float* __restrict__ x) {
  __shared__ int wcount[4];
  int t = threadIdx.x;
  float l = out[t];  // final loss
  bool cond = isfinite(l) && (l <= BETA);
  unsigned long long m = __ballot(cond);
  int lane = t & 63;
  int wv   = t >> 6;
  int pre_in_wave = __popcll(m & ((1ull << lane) - 1ull));
  if (lane == 0) wcount[wv] = (int)__popcll(m);
  __syncthreads();
  int base = 0;
  for (int w = 0; w < wv; ++w) base += wcount[w];
  if (cond) {
    int pos = base + pre_in_wave;  // (M_LEN + prefix) % M_LEN
    float* mrow = out + OFF_MEM + pos * D_OUT;
    const float* erow = enc + t * D_OUT;
    for (int d = 0; d < D_OUT; ++d) mrow[d] = erow[d];
    float* drow = out + OFF_MD + pos * D_IN;
    const float* xrow = x + t * D_IN;
    for (int d = 0; d < D_IN; ++d) drow[d] = xrow[d];
  }
}

// ---------------------------------------------------------------------------
extern "C" void kernel_launch(void* const* d_in, const int* in_sizes, int n_in,
                              void* d_out, int out_size, void* d_ws, size_t ws_size,
                              hipStream_t stream) {
  const float* x      = (const float*)d_in[0];
  const float* mean   = (const float*)d_in[1];
  const float* stdv   = (const float*)d_in[2];
  const float* W1     = (const float*)d_in[3];
  const float* b1     = (const float*)d_in[4];
  const float* memory = (const float*)d_in[5];
  const float* memdat = (const float*)d_in[6];
  float* out = (float*)d_out;
  float* enc = (float*)d_ws;  // 256*256*4 = 256KB scratch

  k_prep<<<dim3(B_ROWS), dim3(256), 0, stream>>>(x, mean, stdv, W1, b1, enc, out);

  k_dist<<<dim3(M_LEN / TM, B_ROWS / TB), dim3(256), 0, stream>>>(
      enc, memory, (const float4*)memory, (const float4*)memdat, out);

  k_scatter<<<dim3(1), dim3(256), 0, stream>>>(out, enc, x);
}

// Round 5
// 27.310 us; speedup vs baseline: 1.7564x; 1.6621x over previous
//
#include <hip/hip_runtime.h>
#include <hip/hip_bf16.h>
#include <math.h>

// Problem constants (from reference setup_inputs)
#define B_ROWS 256
#define D_IN   128
#define D_OUT  256
#define M_LEN  4096
#define BETA   50.0f

// out layout (f32): loss[256] | mem_out[4096*256] | md_out[4096*128]
#define OFF_MEM  (B_ROWS)
#define OFF_MD   (B_ROWS + M_LEN * D_OUT)

// ---------------------------------------------------------------------------
// K1 (k_prep): enc = tanh(norm(x)@W1+b1) and loss init to +inf.
// 256 blocks x 256 threads (one block per batch row).
// ---------------------------------------------------------------------------
__global__ __launch_bounds__(256) void k_prep(
    const float* __restrict__ x, const float* __restrict__ mean,
    const float* __restrict__ stdv, const float* __restrict__ W1,
    const float* __restrict__ b1, float* __restrict__ enc,
    float* __restrict__ out) {
  __shared__ float sx[D_IN];
  const int b = blockIdx.x, j = threadIdx.x;
  if (j < D_IN) {
    float s = stdv[j];
    sx[j] = (s == 0.0f) ? 0.0f : (x[b * D_IN + j] - mean[j]) / s;
  }
  __syncthreads();
  float acc = b1[j];
#pragma unroll 8
  for (int k = 0; k < D_IN; ++k) acc = fmaf(sx[k], W1[k * D_OUT + j], acc);
  enc[b * D_OUT + j] = tanhf(acc);
  if (b == 0) ((unsigned int*)out)[j] = 0x7F800000u;  // +inf loss init
}

// ---------------------------------------------------------------------------
// K2 (k_dist): loss[b] = min_m sum_d |enc[b,d] - memory[m,d]|
// 512 blocks (64 m-tiles x 8 b-tiles) x 256 threads. Tile 32b x 64m.
// k-split 4: wave w owns k in [64w, 64w+64), staged as 2 chunks of 32 into
// its PRIVATE LDS region -> NO barriers in the main loop (waves drift
// freely; SIMD interleaving hides LDS/global latency).
// Per lane: 4x8 microtile (lane = 8 tr x 8 tc); per k: 1+2 ds_read_b128 vs
// 64 arith VALU. LDS k-major with XOR swizzle row^=4*(k>>2): staging b32
// stores and b128 reads both 2-way (free), 16B alignment preserved.
// Global staging loads are 8-lane-contiguous (128B runs, coalesced).
// Cross-wave combine via swizzled scratch in sM + single barrier.
// Also performs the FULL memory->out / mem_data->out copy (loads early,
// stores at the very end).
// ---------------------------------------------------------------------------
#define TB 32
#define TM 64

__global__ __launch_bounds__(256) void k_dist(
    const float* __restrict__ enc, const float* __restrict__ mem,
    const float4* __restrict__ mem4, const float4* __restrict__ md4,
    float* __restrict__ out) {
  __shared__ __align__(16) float sE[4][32][TB];  // [wave][kk][row^swz] 16KB
  __shared__ __align__(16) float sM[4][32][TM];  // [wave][kk][row^swz] 32KB

  const int t  = threadIdx.x;
  const int w  = t >> 6;     // wave id -> k-quarter
  const int l  = t & 63;
  const int ro = l >> 3;     // 0..7 staging row-offset; compute tr
  const int q  = l & 7;      // 0..7 staging f4-k index; compute tc
  const int m0 = blockIdx.x * TM;
  const int b0 = blockIdx.y * TB;
  const int bid = blockIdx.y * 64 + blockIdx.x;  // gridDim.x == 64

  const float* encp = enc + (b0 + ro) * D_OUT + w * 64 + q * 4;
  const float* memp = mem + (m0 + ro) * D_OUT + w * 64 + q * 4;

  float4 rE[4], rM[8], rE2[4], rM2[8];
  float acc[4][8] = {};

  auto store_lds = [&](const float4* e, const float4* m) {
#pragma unroll
    for (int i = 0; i < 4; ++i) {
      const int row = (i * 8 + ro) ^ (q * 4);
      sE[w][q * 4 + 0][row] = e[i].x;
      sE[w][q * 4 + 1][row] = e[i].y;
      sE[w][q * 4 + 2][row] = e[i].z;
      sE[w][q * 4 + 3][row] = e[i].w;
    }
#pragma unroll
    for (int i = 0; i < 8; ++i) {
      const int row = (i * 8 + ro) ^ (q * 4);
      sM[w][q * 4 + 0][row] = m[i].x;
      sM[w][q * 4 + 1][row] = m[i].y;
      sM[w][q * 4 + 2][row] = m[i].z;
      sM[w][q * 4 + 3][row] = m[i].w;
    }
  };

  auto compute = [&]() {
#pragma unroll
    for (int kk = 0; kk < 32; ++kk) {
      const int sw = (kk >> 2) * 4;
      float4 a   = *(const float4*)&sE[w][kk][(ro * 4) ^ sw];
      float4 bv1 = *(const float4*)&sM[w][kk][(q * 8) ^ sw];
      float4 bv2 = *(const float4*)&sM[w][kk][(q * 8 + 4) ^ sw];
      float av[4] = {a.x, a.y, a.z, a.w};
      float bw[8] = {bv1.x, bv1.y, bv1.z, bv1.w, bv2.x, bv2.y, bv2.z, bv2.w};
#pragma unroll
      for (int i = 0; i < 4; ++i)
#pragma unroll
        for (int j = 0; j < 8; ++j)
          acc[i][j] += fabsf(av[i] - bw[j]);
    }
  };

  // chunk 0 loads (coalesced: 8 consecutive lanes = 128B run)
#pragma unroll
  for (int i = 0; i < 4; ++i) rE[i] = *(const float4*)(encp + i * 8 * D_OUT);
#pragma unroll
  for (int i = 0; i < 8; ++i) rM[i] = *(const float4*)(memp + i * 8 * D_OUT);
  store_lds(rE, rM);

  // prefetch chunk 1 (+32 k)
#pragma unroll
  for (int i = 0; i < 4; ++i) rE2[i] = *(const float4*)(encp + 32 + i * 8 * D_OUT);
#pragma unroll
  for (int i = 0; i < 8; ++i) rM2[i] = *(const float4*)(memp + 32 + i * 8 * D_OUT);

  // fused output-copy loads (complete by the tail stores)
  float4 cm0 = mem4[bid * 512 + t];
  float4 cm1 = mem4[bid * 512 + 256 + t];
  float4 cd0 = md4[bid * 256 + t];

  compute();               // chunk 0
  store_lds(rE2, rM2);     // same-wave WAR on LDS: in-order per wave
  compute();               // chunk 1

  // ---- combine across the 4 k-quarter waves ----
  // wave w dumps its 32 partials into its own sM region (no barrier needed:
  // only own-region overwrite after own compute), swizzled for 2-way banks.
  float* sf = &sM[0][0][0];
#pragma unroll
  for (int i = 0; i < 4; ++i)
#pragma unroll
    for (int j = 0; j < 8; ++j) {
      const int p = i * 8 + j;
      sf[w * 2048 + l * 32 + (p ^ (l & 31))] = acc[i][j];
    }
  __syncthreads();

  // summer: thread t handles b-row r = t>>3, m-cols (t&7)*8..+7
  {
    const int r = t >> 3, cg = t & 7;
    const int lv = (r >> 2) * 8 + cg;
    float dmin = 3.4e38f;
#pragma unroll
    for (int j = 0; j < 8; ++j) {
      const int p = (r & 3) * 8 + j;
      float s = sf[0 * 2048 + lv * 32 + (p ^ (lv & 31))];
      s += sf[1 * 2048 + lv * 32 + (p ^ (lv & 31))];
      s += sf[2 * 2048 + lv * 32 + (p ^ (lv & 31))];
      s += sf[3 * 2048 + lv * 32 + (p ^ (lv & 31))];
      dmin = fminf(dmin, s);
    }
    dmin = fminf(dmin, __shfl_xor(dmin, 1));
    dmin = fminf(dmin, __shfl_xor(dmin, 2));
    dmin = fminf(dmin, __shfl_xor(dmin, 4));
    if (cg == 0)  // distances >= 0, init +inf -> uint-bit atomicMin valid
      atomicMin((unsigned int*)out + (b0 + r), __float_as_uint(dmin));
  }

  // ---- complete fused copy ----
  float4* mo = (float4*)(out + OFF_MEM);
  float4* dd = (float4*)(out + OFF_MD);
  mo[bid * 512 + t] = cm0;
  mo[bid * 512 + 256 + t] = cm1;
  dd[bid * 256 + t] = cd0;
}

// ---------------------------------------------------------------------------
// K3 (k_scatter): sequential circular-buffer update collapsed to
// ballot/prefix + scatter (count starts at M_LEN so positions wrap from 0).
// ---------------------------------------------------------------------------
__global__ __launch_bounds__(256) void k_scatter(float* __restrict__ out,
                                                 const float* __restrict__ enc,
                                                 const float* __restrict__ x) {
  __shared__ int wcount[4];
  int t = threadIdx.x;
  float l = out[t];  // final loss
  bool cond = isfinite(l) && (l <= BETA);
  unsigned long long m = __ballot(cond);
  int lane = t & 63;
  int wv   = t >> 6;
  int pre_in_wave = __popcll(m & ((1ull << lane) - 1ull));
  if (lane == 0) wcount[wv] = (int)__popcll(m);
  __syncthreads();
  int base = 0;
  for (int w = 0; w < wv; ++w) base += wcount[w];
  if (cond) {
    int pos = base + pre_in_wave;  // (M_LEN + prefix) % M_LEN
    float* mrow = out + OFF_MEM + pos * D_OUT;
    const float* erow = enc + t * D_OUT;
    for (int d = 0; d < D_OUT; ++d) mrow[d] = erow[d];
    float* drow = out + OFF_MD + pos * D_IN;
    const float* xrow = x + t * D_IN;
    for (int d = 0; d < D_IN; ++d) drow[d] = xrow[d];
  }
}

// ---------------------------------------------------------------------------
extern "C" void kernel_launch(void* const* d_in, const int* in_sizes, int n_in,
                              void* d_out, int out_size, void* d_ws, size_t ws_size,
                              hipStream_t stream) {
  const float* x      = (const float*)d_in[0];
  const float* mean   = (const float*)d_in[1];
  const float* stdv   = (const float*)d_in[2];
  const float* W1     = (const float*)d_in[3];
  const float* b1     = (const float*)d_in[4];
  const float* memory = (const float*)d_in[5];
  const float* memdat = (const float*)d_in[6];
  float* out = (float*)d_out;
  float* enc = (float*)d_ws;  // 256*256*4 = 256KB scratch

  k_prep<<<dim3(B_ROWS), dim3(256), 0, stream>>>(x, mean, stdv, W1, b1, enc, out);

  k_dist<<<dim3(M_LEN / TM, B_ROWS / TB), dim3(256), 0, stream>>>(
      enc, memory, (const float4*)memory, (const float4*)memdat, out);

  k_scatter<<<dim3(1), dim3(256), 0, stream>>>(out, enc, x);
}